// Round 9
// baseline (432.519 us; speedup 1.0000x reference)
//
#include <hip/hip_runtime.h>
#include <math.h>

#define B_ 2
#define S_ 2048
#define D_ 768
#define H_ 12
#define HD_ 64
#define KKEEP 614            // max(1, int(0.3*2048))
#define M_ (B_*S_)           // 4096
#define KD_ 768
#define SRW 2072             // scB row stride in ushorts (4144B rows, 16B aligned)

typedef __attribute__((ext_vector_type(8))) short bf8;   // 8 bf16 = 4 VGPR (MFMA A/B frag)
typedef __attribute__((ext_vector_type(4))) float f4;    // MFMA 16x16 C/D frag

__device__ __forceinline__ unsigned short f2bf(float f) {   // RNE fp32->bf16
    unsigned u = __float_as_uint(f);
    u += 0x7FFF + ((u >> 16) & 1);
    return (unsigned short)(u >> 16);
}
__device__ __forceinline__ float bf2f(unsigned short h) {
    return __uint_as_float((unsigned)h << 16);
}
// fp32 -> orderable-u16 (bf16-RNE in orderable space)
__device__ __forceinline__ unsigned f2ord16(float f) {
    unsigned u = __float_as_uint(f);
    unsigned o32 = u ^ ((unsigned)((int)u >> 31) | 0x80000000u);
    return (o32 + 0x7FFFu + ((o32 >> 16) & 1u)) >> 16;
}
// orderable-u16 -> fp32 (exact bf16 value)
__device__ __forceinline__ float ord16_to_f(unsigned o16) {
    unsigned o = o16 << 16;
    unsigned mask = 0x80000000u | ~(unsigned)((int)o >> 31);
    return __uint_as_float((o ^ mask) & 0xFFFF0000u);
}
// async 16B global->LDS (direct DMA, no VGPR round-trip). LDS dest must be
// wave-contiguous: we pass base+chunkidx*16 where chunkidx = lane-ordered.
__device__ __forceinline__ void gl_lds16(const unsigned short* g, unsigned short* l) {
    __builtin_amdgcn_global_load_lds(
        (const __attribute__((address_space(1))) void*)g,
        (__attribute__((address_space(3))) void*)l, 16, 0, 0);
}

// One launch: split x (NP elems) + 4 weight mats (NW each) into bf16 hi/lo planes
__global__ void split_all(const float* __restrict__ x,
                          const float* __restrict__ w0, const float* __restrict__ w1,
                          const float* __restrict__ w2, const float* __restrict__ w3,
                          unsigned short* __restrict__ xhi, unsigned short* __restrict__ xlo,
                          unsigned short* __restrict__ whi, unsigned short* __restrict__ wlo) {
    const int NPc = M_ * D_;
    const int NWc = D_ * D_;
    int i = blockIdx.x * blockDim.x + threadIdx.x;
    float f;
    unsigned short *ph, *pl;
    int o;
    if (i < NPc) {
        f = x[i]; ph = xhi; pl = xlo; o = i;
    } else {
        int j = i - NPc;
        int which = j / NWc;                       // const-div -> magic mul
        int k = j - which * NWc;
        const float* src = which == 0 ? w0 : which == 1 ? w1 : which == 2 ? w2 : w3;
        f = src[k]; ph = whi; pl = wlo; o = j;
    }
    unsigned short h = f2bf(f);
    ph[o] = h;
    pl[o] = f2bf(f - bf2f(h));
}

// Fused Q/K/V projection: C[m][n] = sum_k x[m][k]*Wcat[n][k] + bias, split-bf16
// (3 MFMA/product). Tile 128(M) x 64(N); grid.y in [0,36): which = y/12.
//   which 0 (Q): BHSD hi+lo, PRE-SCALED by 0.125
//   which 1 (K): BHSD hi     which 2 (V): BHDS hi
__global__ __launch_bounds__(256)
void gemm_qkv(const unsigned short* __restrict__ Ahi, const unsigned short* __restrict__ Alo,
              const unsigned short* __restrict__ Wch, const unsigned short* __restrict__ Wcl,
              const float* __restrict__ bq, const float* __restrict__ bk,
              const float* __restrict__ bv,
              unsigned short* __restrict__ Qh, unsigned short* __restrict__ Ql,
              unsigned short* __restrict__ Kh, unsigned short* __restrict__ Vth) {
    __shared__ __align__(16) unsigned short Ah[128][32], Al[128][32], Bh[64][32], Bl[64][32];
    const int bm = blockIdx.x * 128, bnG = blockIdx.y * 64;
    const int which = blockIdx.y / 12;                  // 0=Q 1=K 2=V
    const int bn = bnG - which * 768;                   // local col tile base
    const float* bias = which == 0 ? bq : (which == 1 ? bk : bv);
    const int tid = threadIdx.x, lane = tid & 63, wave = tid >> 6;
    const int col = lane & 15, quad = lane >> 4;

    f4 acc[2][4];
#pragma unroll
    for (int mi = 0; mi < 2; ++mi)
#pragma unroll
        for (int ni = 0; ni < 4; ++ni) { f4 z = {0.f,0.f,0.f,0.f}; acc[mi][ni] = z; }

    for (int kt = 0; kt < KD_; kt += 32) {
        __syncthreads();
        // async stage: LDS offset == chunkidx*16B (wave-contiguous by construction)
#pragma unroll
        for (int c = 0; c < 2; ++c) {
            int idx = c * 256 + tid;
            int row = idx >> 2, ko = (idx & 3) * 8;
            gl_lds16(&Ahi[(size_t)(bm + row) * KD_ + kt + ko], &Ah[0][0] + idx * 8);
            gl_lds16(&Alo[(size_t)(bm + row) * KD_ + kt + ko], &Al[0][0] + idx * 8);
        }
        {
            int row = tid >> 2, ko = (tid & 3) * 8;
            gl_lds16(&Wch[(size_t)(bnG + row) * KD_ + kt + ko], &Bh[0][0] + tid * 8);
            gl_lds16(&Wcl[(size_t)(bnG + row) * KD_ + kt + ko], &Bl[0][0] + tid * 8);
        }
        __syncthreads();   // drains vmcnt incl. global_load_lds

        bf8 af[2][2], wf[4][2];
#pragma unroll
        for (int mi = 0; mi < 2; ++mi) {
            int r = wave * 32 + mi * 16 + col;
            af[mi][0] = *(const bf8*)&Ah[r][quad * 8];
            af[mi][1] = *(const bf8*)&Al[r][quad * 8];
        }
#pragma unroll
        for (int ni = 0; ni < 4; ++ni) {
            int r = ni * 16 + col;
            wf[ni][0] = *(const bf8*)&Bh[r][quad * 8];
            wf[ni][1] = *(const bf8*)&Bl[r][quad * 8];
        }
#pragma unroll
        for (int mi = 0; mi < 2; ++mi)
#pragma unroll
            for (int ni = 0; ni < 4; ++ni) {
                acc[mi][ni] = __builtin_amdgcn_mfma_f32_16x16x32_bf16(af[mi][0], wf[ni][0], acc[mi][ni], 0, 0, 0);
                acc[mi][ni] = __builtin_amdgcn_mfma_f32_16x16x32_bf16(af[mi][1], wf[ni][0], acc[mi][ni], 0, 0, 0);
                acc[mi][ni] = __builtin_amdgcn_mfma_f32_16x16x32_bf16(af[mi][0], wf[ni][1], acc[mi][ni], 0, 0, 0);
            }
    }

    float bvv[4];
#pragma unroll
    for (int ni = 0; ni < 4; ++ni) bvv[ni] = bias[bn + ni * 16 + col];
#pragma unroll
    for (int mi = 0; mi < 2; ++mi)
#pragma unroll
        for (int ni = 0; ni < 4; ++ni)
#pragma unroll
            for (int r = 0; r < 4; ++r) {
                int m = bm + wave * 32 + mi * 16 + quad * 4 + r;  // C row = quad*4+reg
                int n = bn + ni * 16 + col;                       // C col = lane&15
                float v = acc[mi][ni][r] + bvv[ni];
                if (which == 0) v *= 0.125f;                      // fold 1/sqrt(64)
                int b = m >> 11, s = m & 2047, h = n >> 6, d = n & 63;
                unsigned short hh = f2bf(v);
                if (which == 0) {
                    size_t idx = (((size_t)b * H_ + h) * S_ + s) * HD_ + d;
                    Qh[idx] = hh;
                    Ql[idx] = f2bf(v - bf2f(hh));
                } else if (which == 1) {
                    Kh[(((size_t)b * H_ + h) * S_ + s) * HD_ + d] = hh;
                } else {
                    Vth[(((size_t)b * H_ + h) * HD_ + d) * S_ + s] = hh;
                }
            }
}

// O-projection: fp32 out = AO @ Wo^T + bo (split-bf16, 3 MFMA)
__global__ __launch_bounds__(256)
void gemm_o(const unsigned short* __restrict__ Ahi, const unsigned short* __restrict__ Alo,
            const unsigned short* __restrict__ Whi, const unsigned short* __restrict__ Wlo,
            const float* __restrict__ bias, float* __restrict__ outf) {
    __shared__ __align__(16) unsigned short Ah[128][32], Al[128][32], Bh[64][32], Bl[64][32];
    const int bm = blockIdx.x * 128, bn = blockIdx.y * 64;
    const int tid = threadIdx.x, lane = tid & 63, wave = tid >> 6;
    const int col = lane & 15, quad = lane >> 4;

    f4 acc[2][4];
#pragma unroll
    for (int mi = 0; mi < 2; ++mi)
#pragma unroll
        for (int ni = 0; ni < 4; ++ni) { f4 z = {0.f,0.f,0.f,0.f}; acc[mi][ni] = z; }

    for (int kt = 0; kt < KD_; kt += 32) {
        __syncthreads();
#pragma unroll
        for (int c = 0; c < 2; ++c) {
            int idx = c * 256 + tid;
            int row = idx >> 2, ko = (idx & 3) * 8;
            gl_lds16(&Ahi[(size_t)(bm + row) * KD_ + kt + ko], &Ah[0][0] + idx * 8);
            gl_lds16(&Alo[(size_t)(bm + row) * KD_ + kt + ko], &Al[0][0] + idx * 8);
        }
        {
            int row = tid >> 2, ko = (tid & 3) * 8;
            gl_lds16(&Whi[(size_t)(bn + row) * KD_ + kt + ko], &Bh[0][0] + tid * 8);
            gl_lds16(&Wlo[(size_t)(bn + row) * KD_ + kt + ko], &Bl[0][0] + tid * 8);
        }
        __syncthreads();

        bf8 af[2][2], wf[4][2];
#pragma unroll
        for (int mi = 0; mi < 2; ++mi) {
            int r = wave * 32 + mi * 16 + col;
            af[mi][0] = *(const bf8*)&Ah[r][quad * 8];
            af[mi][1] = *(const bf8*)&Al[r][quad * 8];
        }
#pragma unroll
        for (int ni = 0; ni < 4; ++ni) {
            int r = ni * 16 + col;
            wf[ni][0] = *(const bf8*)&Bh[r][quad * 8];
            wf[ni][1] = *(const bf8*)&Bl[r][quad * 8];
        }
#pragma unroll
        for (int mi = 0; mi < 2; ++mi)
#pragma unroll
            for (int ni = 0; ni < 4; ++ni) {
                acc[mi][ni] = __builtin_amdgcn_mfma_f32_16x16x32_bf16(af[mi][0], wf[ni][0], acc[mi][ni], 0, 0, 0);
                acc[mi][ni] = __builtin_amdgcn_mfma_f32_16x16x32_bf16(af[mi][1], wf[ni][0], acc[mi][ni], 0, 0, 0);
                acc[mi][ni] = __builtin_amdgcn_mfma_f32_16x16x32_bf16(af[mi][0], wf[ni][1], acc[mi][ni], 0, 0, 0);
            }
    }

    float bvv[4];
#pragma unroll
    for (int ni = 0; ni < 4; ++ni) bvv[ni] = bias[bn + ni * 16 + col];
#pragma unroll
    for (int mi = 0; mi < 2; ++mi)
#pragma unroll
        for (int ni = 0; ni < 4; ++ni)
#pragma unroll
            for (int r = 0; r < 4; ++r) {
                int m = bm + wave * 32 + mi * 16 + quad * 4 + r;
                int n = bn + ni * 16 + col;
                outf[(size_t)m * D_ + n] = acc[mi][ni][r] + bvv[ni];
            }
}

// Attention: block = 16 q rows of one (b,h); 1024 thr = 16 waves; wave owns 128 keys
// for QK, then one full row for selection. Ballot+popcount counting (VALU cmp +
// SALU bcnt), EARLY-EXIT when cnt==KKEEP (exact: selected set already final).
__global__ __launch_bounds__(1024, 8)
void attn_kernel(const unsigned short* __restrict__ Qhi, const unsigned short* __restrict__ Qlo,
                 const unsigned short* __restrict__ Khi,
                 const unsigned short* __restrict__ Vthi,
                 unsigned short* __restrict__ AOhi, unsigned short* __restrict__ AOlo) {
    const int bid = blockIdx.x;            // 3072 = 24 bh * 128 q-tiles
    const int xcd = bid & 7, sub = (bid >> 3) % 3, tile = bid / 24;
    const int bh = xcd * 3 + sub;          // L2 locality: 3 (b,h) per XCD
    const int b = bh / H_, h = bh % H_;
    const int q0 = tile * 16;
    const int tid = threadIdx.x, lane = tid & 63, wave = tid >> 6;   // wave 0..15
    const int col = lane & 15, quad = lane >> 4;

    __shared__ __align__(16) unsigned char arena[16 * 4144];   // 66.3KB
    unsigned short* scB = (unsigned short*)arena;              // [16][SRW] u16
    float (*osum)[16][64] = (float (*)[16][64])arena;          // [16][16][64] f32 (64KB)
    __shared__ float linv[16];

    // Q A-frags direct from global: m = col = q-local, k = quad*8+j  (Q pre-scaled)
    const size_t qbase = ((size_t)bh * S_ + q0 + col) * HD_;
    bf8 qh0 = *(const bf8*)&Qhi[qbase + quad * 8];
    bf8 qh1 = *(const bf8*)&Qhi[qbase + 32 + quad * 8];
    bf8 ql0 = *(const bf8*)&Qlo[qbase + quad * 8];
    bf8 ql1 = *(const bf8*)&Qlo[qbase + 32 + quad * 8];

    // ---- QK^T (4-MFMA split): q = quad*4+r, key = wave*128 + t*16 + col ----
    const size_t kbb = (size_t)bh * S_ * HD_;
#pragma unroll 1
    for (int t = 0; t < 8; ++t) {
        const size_t kr = kbb + (size_t)(wave * 128 + t * 16 + col) * HD_;
        bf8 kh0 = *(const bf8*)&Khi[kr + quad * 8];
        bf8 kh1 = *(const bf8*)&Khi[kr + 32 + quad * 8];
        f4 a = {0.f, 0.f, 0.f, 0.f};
        a = __builtin_amdgcn_mfma_f32_16x16x32_bf16(qh0, kh0, a, 0, 0, 0);
        a = __builtin_amdgcn_mfma_f32_16x16x32_bf16(qh1, kh1, a, 0, 0, 0);
        a = __builtin_amdgcn_mfma_f32_16x16x32_bf16(ql0, kh0, a, 0, 0, 0);
        a = __builtin_amdgcn_mfma_f32_16x16x32_bf16(ql1, kh1, a, 0, 0, 0);
#pragma unroll
        for (int r = 0; r < 4; ++r)
            scB[(quad * 4 + r) * SRW + wave * 128 + t * 16 + col] =
                (unsigned short)f2ord16(a[r]);
    }
    __syncthreads();                                       // [1] transpose visible

    // ---- wave w owns row w: kv[16] packed dwords + pre-shifted kvs[16] ----
    unsigned* rowp = (unsigned*)(arena + wave * 4144);
    unsigned kv[16], kvs[16];
#pragma unroll
    for (int j = 0; j < 16; ++j) kv[j] = rowp[lane + 64 * j];   // conflict-free
#pragma unroll
    for (int j = 0; j < 16; ++j) kvs[j] = kv[j] << 16;

    // row max: u32 max's high half = max of high halves (lexicographic dominance)
    unsigned Mhi = 0, Mlo = 0;
#pragma unroll
    for (int j = 0; j < 16; ++j) {
        Mhi = kv[j]  > Mhi ? kv[j]  : Mhi;
        Mlo = kvs[j] > Mlo ? kvs[j] : Mlo;
    }
    unsigned mo = (Mhi >> 16) > (Mlo >> 16) ? (Mhi >> 16) : (Mlo >> 16);
#pragma unroll
    for (int off = 1; off < 64; off <<= 1) {
        unsigned v = __shfl_xor((int)mo, off, 64);
        mo = mo > v ? mo : v;
    }

    // ---- threshold: largest T with count(>=T) >= KKEEP; ballot+popcount ----
    // Early exit when cnt == KKEEP: the set {k >= T} is already the final set
    // (counts monotone in T; any further-accepted T' has the same 614 keys).
    unsigned T = 0;
#pragma unroll 1
    for (int bit = 15; bit >= 0; --bit) {
        unsigned candh = (T | (1u << bit)) << 16;
        int cnt = 0;
#pragma unroll
        for (int j = 0; j < 16; ++j) {
            cnt += __popcll(__ballot(kv[j]  >= candh));    // hi halves
            cnt += __popcll(__ballot(kvs[j] >= candh));    // lo halves
        }
        if (cnt >= KKEEP) {
            T |= (1u << bit);
            if (cnt == KKEEP) break;
        }
    }

    // ---- weights: w = exp2(fma(s,log2e,-m*log2e)) if key >= T else 0 ----
    const float L2E = 1.44269504f;
    const float mb = ord16_to_f(mo) * L2E;
    float ls = 0.f;
#pragma unroll 1
    for (int j = 0; j < 16; ++j) {
        unsigned lo16 = kv[j] & 0xFFFFu;
        unsigned hi16 = kv[j] >> 16;
        float wl = __builtin_amdgcn_exp2f(__builtin_fmaf(ord16_to_f(lo16), L2E, -mb));
        float wh = __builtin_amdgcn_exp2f(__builtin_fmaf(ord16_to_f(hi16), L2E, -mb));
        wl = (lo16 >= T) ? wl : 0.f;
        wh = (hi16 >= T) ? wh : 0.f;
        ls += wl + wh;
        rowp[lane + 64 * j] = (unsigned)f2bf(wl) | ((unsigned)f2bf(wh) << 16);
    }
#pragma unroll
    for (int off = 1; off < 64; off <<= 1) ls += __shfl_xor(ls, off, 64);
    if (lane == 0) linv[wave] = 1.f / ls;
    __syncthreads();                                       // [2] weights + linv visible

    // ---- PV: A-frags (P) from scB via b128; B-frags (V^T) from global ----
    f4 od[4];
#pragma unroll
    for (int dt = 0; dt < 4; ++dt) { f4 z = {0.f,0.f,0.f,0.f}; od[dt] = z; }
    const size_t vbb = (size_t)bh * HD_ * S_;
#pragma unroll 1
    for (int c = 0; c < 4; ++c) {
        bf8 ph = *(const bf8*)&scB[col * SRW + wave * 128 + c * 32 + quad * 8];
        const size_t sbase = (size_t)(wave * 128 + c * 32 + quad * 8);
#pragma unroll
        for (int dt = 0; dt < 4; ++dt) {
            bf8 vh = *(const bf8*)&Vthi[vbb + (size_t)(dt * 16 + col) * S_ + sbase];
            od[dt] = __builtin_amdgcn_mfma_f32_16x16x32_bf16(ph, vh, od[dt], 0, 0, 0);
        }
    }
    __syncthreads();                                       // [3] all scB reads done
#pragma unroll
    for (int dt = 0; dt < 4; ++dt)
#pragma unroll
        for (int r = 0; r < 4; ++r)
            osum[wave][quad * 4 + r][dt * 16 + col] = od[dt][r];
    __syncthreads();                                       // [4] partials visible

    // ---- final: 1024 threads cover 16x64 (q,d); sum 16 partials, emit planes ----
    {
        int q = tid >> 6, d = tid & 63;
        float s = 0.f;
#pragma unroll
        for (int w = 0; w < 16; ++w) s += osum[w][q][d];
        s *= linv[q];
        size_t idx = ((size_t)b * S_ + q0 + q) * D_ + h * HD_ + d;
        unsigned short hh = f2bf(s);
        AOhi[idx] = hh;
        AOlo[idx] = f2bf(s - bf2f(hh));
    }
}

extern "C" void kernel_launch(void* const* d_in, const int* in_sizes, int n_in,
                              void* d_out, int out_size, void* d_ws, size_t ws_size,
                              hipStream_t stream) {
    const float* x  = (const float*)d_in[0];
    const float* Wq = (const float*)d_in[1];
    const float* bq = (const float*)d_in[2];
    const float* Wk = (const float*)d_in[3];
    const float* bk = (const float*)d_in[4];
    const float* Wv = (const float*)d_in[5];
    const float* bv = (const float*)d_in[6];
    const float* Wo = (const float*)d_in[7];
    const float* bo = (const float*)d_in[8];
    float* out = (float*)d_out;

    const size_t NP = (size_t)M_ * D_;      // 3,145,728 elems
    const size_t NW = (size_t)D_ * D_;      // 589,824 elems
    unsigned short* p = (unsigned short*)d_ws;
    unsigned short* xhi = p;  p += NP;
    unsigned short* xlo = p;  p += NP;
    unsigned short* Wch = p;  p += 4 * NW;   // concatenated [Wq|Wk|Wv|Wo] hi
    unsigned short* Wcl = p;  p += 4 * NW;   // concatenated lo
    unsigned short* Qh  = p;  p += NP;  unsigned short* Ql  = p;  p += NP;
    unsigned short* Kh  = p;  p += NP;
    unsigned short* Vth = p;  p += NP;
    // AO planes alias x planes (x dead after the projections)
    unsigned short* AOh = xhi;
    unsigned short* AOl = xlo;

    {
        int total = (int)(NP + 4 * NW);      // 5,505,024 (multiple of 256)
        split_all<<<total / 256, 256, 0, stream>>>(x, Wq, Wk, Wv, Wo,
                                                   xhi, xlo, Wch, Wcl);
    }

    {
        dim3 g(M_ / 128, 36);               // 3 x 768/64 column tiles
        gemm_qkv<<<g, 256, 0, stream>>>(xhi, xlo, Wch, Wcl, bq, bk, bv,
                                        Qh, Ql, Kh, Vth);
    }

    attn_kernel<<<(S_ / 16) * B_ * H_, 1024, 0, stream>>>(Qh, Ql, Kh, Vth, AOh, AOl);

    {
        dim3 g(M_ / 128, D_ / 64);
        gemm_o<<<g, 256, 0, stream>>>(AOh, AOl, Wch + 3 * NW, Wcl + 3 * NW, bo, out);
    }
}